// Round 2
// baseline (331.147 us; speedup 1.0000x reference)
//
#include <hip/hip_runtime.h>
#include <math.h>

#define EPS 1e-5f

// Problem shapes (fixed for this bench)
constexpr int B   = 2;
constexpr int Ca  = 512;
constexpr int T   = 256;
constexpr int Fa  = 128;
constexpr int Tv  = 64;
constexpr int CHW = T * Fa;          // per-(b,c) audio plane  = 32768
constexpr int NSTAT = B * CHW;       // elements per channel for BN stats = 65536
constexpr int VID_PER_B = Ca * Tv;   // 32768

// ------------------------------------------------------------------
// Kernel 1: per-channel audio sum/sumsq  ->  BN affine coefficients
// ws[0..512)    = s_v   (value scale)
// ws[512..1024) = b_v   (value bias)
// ws[1024..1536)= s_g   (gate scale)
// ws[1536..2048)= b_g   (gate bias)
// ------------------------------------------------------------------
__global__ __launch_bounds__(256) void k_stats(
    const float* __restrict__ audio,
    const float* __restrict__ vw, const float* __restrict__ vg, const float* __restrict__ vb,
    const float* __restrict__ gw, const float* __restrict__ gg, const float* __restrict__ gb,
    float* __restrict__ ws)
{
    const int c   = blockIdx.x;
    const int tid = threadIdx.x;
    const float4* a4 = reinterpret_cast<const float4*>(audio);

    float s = 0.f, s2 = 0.f;
    #pragma unroll
    for (int b = 0; b < B; ++b) {
        const float4* base = a4 + ((size_t)(b * Ca + c) * CHW) / 4;
        for (int k = tid; k < CHW / 4; k += 256) {
            float4 v = base[k];
            s  += v.x + v.y + v.z + v.w;
            s2 += v.x * v.x + v.y * v.y + v.z * v.z + v.w * v.w;
        }
    }
    // wave (64-lane) reduce
    for (int off = 32; off; off >>= 1) {
        s  += __shfl_xor(s,  off);
        s2 += __shfl_xor(s2, off);
    }
    __shared__ float ls[4], ls2[4];
    const int wid = tid >> 6;
    if ((tid & 63) == 0) { ls[wid] = s; ls2[wid] = s2; }
    __syncthreads();
    if (tid == 0) {
        float S  = ls[0]  + ls[1]  + ls[2]  + ls[3];
        float S2 = ls2[0] + ls2[1] + ls2[2] + ls2[3];
        const float inv  = 1.f / (float)NSTAT;
        float mean = S * inv;
        float var  = S2 * inv - mean * mean;

        // value branch: BN(audio * w) = audio * s_v + b_v
        float w  = vw[c];
        float rs = rsqrtf(w * w * var + EPS);
        float sv = w * rs * vg[c];
        ws[c]        = sv;
        ws[512 + c]  = vb[c] - mean * sv;

        // gate branch
        w  = gw[c];
        rs = rsqrtf(w * w * var + EPS);
        float sg = w * rs * gg[c];
        ws[1024 + c] = sg;
        ws[1536 + c] = gb[c] - mean * sg;
    }
}

// ------------------------------------------------------------------
// Kernel 2: video branches.  One block per sample b (1024 threads).
// thread = (c_local, t) with t = tid&63 (one softmax row == one wave)
// Writes att (softmaxed) and vr (GN'd) at Tv resolution.
// ------------------------------------------------------------------
__global__ __launch_bounds__(1024) void k_video(
    const float* __restrict__ video,
    const float* __restrict__ aw, const float* __restrict__ ab,
    const float* __restrict__ ag, const float* __restrict__ abeta,
    const float* __restrict__ rw, const float* __restrict__ rb,
    const float* __restrict__ rg, const float* __restrict__ rbeta,
    float* __restrict__ att_out, float* __restrict__ vr_out)
{
    const int b   = blockIdx.x;
    const int tid = threadIdx.x;
    const int t   = tid & 63;
    const int cl  = tid >> 6;          // 0..15
    const float* vbase = video + (size_t)b * VID_PER_B;

    // phase 1: GN stats for both branches
    float s1a = 0.f, s2a = 0.f, s1r = 0.f, s2r = 0.f;
    #pragma unroll
    for (int i = 0; i < Ca / 16; ++i) {
        const int c = cl + 16 * i;
        float v  = vbase[c * Tv + t];
        float xa = v * aw[c] + ab[c];
        float xr = v * rw[c] + rb[c];
        s1a += xa; s2a += xa * xa;
        s1r += xr; s2r += xr * xr;
    }
    for (int off = 32; off; off >>= 1) {
        s1a += __shfl_xor(s1a, off); s2a += __shfl_xor(s2a, off);
        s1r += __shfl_xor(s1r, off); s2r += __shfl_xor(s2r, off);
    }
    __shared__ float red[4][16];
    __shared__ float stats[4];
    const int wid = tid >> 6;
    if ((tid & 63) == 0) {
        red[0][wid] = s1a; red[1][wid] = s2a;
        red[2][wid] = s1r; red[3][wid] = s2r;
    }
    __syncthreads();
    if (tid == 0) {
        float S1a = 0, S2a = 0, S1r = 0, S2r = 0;
        for (int i = 0; i < 16; ++i) {
            S1a += red[0][i]; S2a += red[1][i];
            S1r += red[2][i]; S2r += red[3][i];
        }
        const float inv = 1.f / (float)VID_PER_B;
        float ma = S1a * inv, va = S2a * inv - ma * ma;
        float mr = S1r * inv, vv = S2r * inv - mr * mr;
        stats[0] = ma; stats[1] = rsqrtf(va + EPS);
        stats[2] = mr; stats[3] = rsqrtf(vv + EPS);
    }
    __syncthreads();
    const float ma = stats[0], rsa = stats[1];
    const float mr = stats[2], rsr = stats[3];

    // phase 2: normalize, softmax(att) over t within the wave, store
    #pragma unroll
    for (int i = 0; i < Ca / 16; ++i) {
        const int c = cl + 16 * i;
        float v  = vbase[c * Tv + t];
        float xa = (v * aw[c] + ab[c] - ma) * rsa * ag[c] + abeta[c];
        float xr = (v * rw[c] + rb[c] - mr) * rsr * rg[c] + rbeta[c];

        float m = xa;
        for (int off = 32; off; off >>= 1) m = fmaxf(m, __shfl_xor(m, off));
        float e = expf(xa - m);
        float sum = e;
        for (int off = 32; off; off >>= 1) sum += __shfl_xor(sum, off);

        const size_t idx = (size_t)b * VID_PER_B + (size_t)c * Tv + t;
        att_out[idx] = e / sum;
        vr_out[idx]  = xr;
    }
}

// ------------------------------------------------------------------
// Kernel 3: fused output
// out[b,c,t,f] = att[b,c,t>>2]*(a*s_v+b_v) + relu(a*s_g+b_g)*vr[b,c,t>>2]
// Each block handles 1024 contiguous float4 (16 KiB); thread does 4 f4
// at stride 256 for coalescing.
// ------------------------------------------------------------------
__global__ __launch_bounds__(256) void k_fuse(
    const float* __restrict__ audio,
    const float* __restrict__ ws,
    const float* __restrict__ att, const float* __restrict__ vr,
    float* __restrict__ out)
{
    const float4* a4 = reinterpret_cast<const float4*>(audio);
    float4*       o4 = reinterpret_cast<float4*>(out);
    const size_t base = (size_t)blockIdx.x * 1024 + threadIdx.x;

    #pragma unroll
    for (int k = 0; k < 4; ++k) {
        const size_t i  = base + (size_t)k * 256;   // float4 index
        const size_t t4 = i >> 5;                   // (b*Ca + c)*T + t   (Fa/4 = 32)
        const int    t  = (int)(t4 & (size_t)(T - 1));
        const size_t bc = t4 >> 8;                  // b*Ca + c           (T = 256)
        const int    c  = (int)(bc & (size_t)(Ca - 1));

        const float sv = ws[c];
        const float bv = ws[512 + c];
        const float sg = ws[1024 + c];
        const float bg = ws[1536 + c];

        const size_t vidx = bc * Tv + (size_t)(t >> 2);
        const float av = att[vidx];
        const float vv = vr[vidx];

        float4 a = a4[i];
        float4 r;
        r.x = av * (a.x * sv + bv) + fmaxf(a.x * sg + bg, 0.f) * vv;
        r.y = av * (a.y * sv + bv) + fmaxf(a.y * sg + bg, 0.f) * vv;
        r.z = av * (a.z * sv + bv) + fmaxf(a.z * sg + bg, 0.f) * vv;
        r.w = av * (a.w * sv + bv) + fmaxf(a.w * sg + bg, 0.f) * vv;
        o4[i] = r;
    }
}

// ------------------------------------------------------------------
extern "C" void kernel_launch(void* const* d_in, const int* in_sizes, int n_in,
                              void* d_out, int out_size, void* d_ws, size_t ws_size,
                              hipStream_t stream) {
    const float* audio   = (const float*)d_in[0];
    const float* video   = (const float*)d_in[1];
    const float* value_w = (const float*)d_in[2];
    const float* value_g = (const float*)d_in[3];
    const float* value_b = (const float*)d_in[4];
    const float* gate_w  = (const float*)d_in[5];
    const float* gate_g  = (const float*)d_in[6];
    const float* gate_b  = (const float*)d_in[7];
    const float* att_w   = (const float*)d_in[8];
    const float* att_b   = (const float*)d_in[9];
    const float* att_g   = (const float*)d_in[10];
    const float* att_be  = (const float*)d_in[11];
    const float* res_w   = (const float*)d_in[12];
    const float* res_b   = (const float*)d_in[13];
    const float* res_g   = (const float*)d_in[14];
    const float* res_be  = (const float*)d_in[15];

    float* ws  = (float*)d_ws;          // 2048 floats of affine coeffs
    float* att = ws + 2048;             // B*Ca*Tv
    float* vrr = att + (size_t)B * VID_PER_B;

    k_stats<<<Ca, 256, 0, stream>>>(audio, value_w, value_g, value_b,
                                    gate_w, gate_g, gate_b, ws);
    k_video<<<B, 1024, 0, stream>>>(video, att_w, att_b, att_g, att_be,
                                    res_w, res_b, res_g, res_be, att, vrr);

    const int total_f4  = B * Ca * T * Fa / 4;      // 8388608
    const int blocks    = total_f4 / 1024;          // 8192
    k_fuse<<<blocks, 256, 0, stream>>>(audio, ws, att, vrr, (float*)d_out);
}

// Round 4
// 316.289 us; speedup vs baseline: 1.0470x; 1.0470x over previous
//
#include <hip/hip_runtime.h>
#include <math.h>

#define EPS 1e-5f

typedef float f32x4 __attribute__((ext_vector_type(4)));

// Problem shapes (fixed for this bench)
constexpr int B   = 2;
constexpr int Ca  = 512;
constexpr int T   = 256;
constexpr int Fa  = 128;
constexpr int Tv  = 64;
constexpr int CHW = T * Fa;          // per-(b,c) audio plane = 32768 floats
constexpr int NSTAT = B * CHW;       // elements per channel for BN stats
constexpr int VID_PER_B = Ca * Tv;   // 32768

// workspace layout (floats):
//  [0..2048)     coef: sv | bv | sg | bg  (512 each)
//  [2048..4096)  partial sums  s   (2048 blocks)
//  [4096..6144)  partial sums  s2
//  [6144..71680) att  (B*Ca*Tv = 65536)
//  [71680..137216) vr
constexpr int WS_COEF = 0;
constexpr int WS_PS   = 2048;
constexpr int WS_PS2  = 4096;
constexpr int WS_ATT  = 6144;
constexpr int WS_VR   = WS_ATT + B * VID_PER_B;

// ------------------------------------------------------------------
// Kernel 1: partial per-channel sum/sumsq. 2048 blocks, one per
// half-plane (4096 float4 = 64 KiB contiguous). No atomics.
// partial index for (b,c,half) = b*1024 + c*2 + half == blockIdx.x
// ------------------------------------------------------------------
__global__ __launch_bounds__(256) void k_stats(
    const float* __restrict__ audio, float* __restrict__ ws)
{
    const int blk = blockIdx.x;
    const int tid = threadIdx.x;
    const f32x4* a4 = reinterpret_cast<const f32x4*>(audio) + (size_t)blk * 4096;

    float s = 0.f, s2 = 0.f;
    #pragma unroll
    for (int k = 0; k < 16; ++k) {
        f32x4 v = a4[tid + k * 256];
        s  += v.x + v.y + v.z + v.w;
        s2 += v.x * v.x + v.y * v.y + v.z * v.z + v.w * v.w;
    }
    for (int off = 32; off; off >>= 1) {
        s  += __shfl_xor(s,  off);
        s2 += __shfl_xor(s2, off);
    }
    __shared__ float ls[4], ls2[4];
    const int wid = tid >> 6;
    if ((tid & 63) == 0) { ls[wid] = s; ls2[wid] = s2; }
    __syncthreads();
    if (tid == 0) {
        ws[WS_PS  + blk] = ls[0]  + ls[1]  + ls[2]  + ls[3];
        ws[WS_PS2 + blk] = ls2[0] + ls2[1] + ls2[2] + ls2[3];
    }
}

// ------------------------------------------------------------------
// Kernel 2: video branches + BN coefficient reduction (block 0).
// One block per sample b (1024 threads); t = tid&63 -> one softmax
// row per wave.
// ------------------------------------------------------------------
__global__ __launch_bounds__(1024) void k_video(
    const float* __restrict__ video,
    const float* __restrict__ vw, const float* __restrict__ vg, const float* __restrict__ vb,
    const float* __restrict__ gw, const float* __restrict__ gg, const float* __restrict__ gb,
    const float* __restrict__ aw, const float* __restrict__ ab,
    const float* __restrict__ ag, const float* __restrict__ abeta,
    const float* __restrict__ rw, const float* __restrict__ rb,
    const float* __restrict__ rg, const float* __restrict__ rbeta,
    float* __restrict__ ws)
{
    const int b   = blockIdx.x;
    const int tid = threadIdx.x;

    // ---- BN coefficient computation (depends on k_stats via stream order)
    if (b == 0 && tid < Ca) {
        const int c = tid;
        const float S  = ws[WS_PS  + c*2] + ws[WS_PS  + c*2 + 1]
                       + ws[WS_PS  + 1024 + c*2] + ws[WS_PS  + 1024 + c*2 + 1];
        const float S2 = ws[WS_PS2 + c*2] + ws[WS_PS2 + c*2 + 1]
                       + ws[WS_PS2 + 1024 + c*2] + ws[WS_PS2 + 1024 + c*2 + 1];
        const float inv  = 1.f / (float)NSTAT;
        const float mean = S * inv;
        const float var  = S2 * inv - mean * mean;

        float w  = vw[c];
        float sv = w * rsqrtf(w * w * var + EPS) * vg[c];
        ws[WS_COEF + c]        = sv;
        ws[WS_COEF + 512 + c]  = vb[c] - mean * sv;

        w = gw[c];
        float sg = w * rsqrtf(w * w * var + EPS) * gg[c];
        ws[WS_COEF + 1024 + c] = sg;
        ws[WS_COEF + 1536 + c] = gb[c] - mean * sg;
    }

    // ---- video GN + softmax
    const int t  = tid & 63;
    const int cl = tid >> 6;           // 0..15
    const float* vbase = video + (size_t)b * VID_PER_B;
    float* att_out = ws + WS_ATT;
    float* vr_out  = ws + WS_VR;

    float s1a = 0.f, s2a = 0.f, s1r = 0.f, s2r = 0.f;
    #pragma unroll
    for (int i = 0; i < Ca / 16; ++i) {
        const int c = cl + 16 * i;
        float v  = vbase[c * Tv + t];
        float xa = v * aw[c] + ab[c];
        float xr = v * rw[c] + rb[c];
        s1a += xa; s2a += xa * xa;
        s1r += xr; s2r += xr * xr;
    }
    for (int off = 32; off; off >>= 1) {
        s1a += __shfl_xor(s1a, off); s2a += __shfl_xor(s2a, off);
        s1r += __shfl_xor(s1r, off); s2r += __shfl_xor(s2r, off);
    }
    __shared__ float red[4][16];
    __shared__ float stats[4];
    const int wid = tid >> 6;
    if ((tid & 63) == 0) {
        red[0][wid] = s1a; red[1][wid] = s2a;
        red[2][wid] = s1r; red[3][wid] = s2r;
    }
    __syncthreads();
    if (tid == 0) {
        float S1a = 0, S2a = 0, S1r = 0, S2r = 0;
        for (int i = 0; i < 16; ++i) {
            S1a += red[0][i]; S2a += red[1][i];
            S1r += red[2][i]; S2r += red[3][i];
        }
        const float inv = 1.f / (float)VID_PER_B;
        float ma = S1a * inv, va = S2a * inv - ma * ma;
        float mr = S1r * inv, vv = S2r * inv - mr * mr;
        stats[0] = ma; stats[1] = rsqrtf(va + EPS);
        stats[2] = mr; stats[3] = rsqrtf(vv + EPS);
    }
    __syncthreads();
    const float ma = stats[0], rsa = stats[1];
    const float mr = stats[2], rsr = stats[3];

    #pragma unroll
    for (int i = 0; i < Ca / 16; ++i) {
        const int c = cl + 16 * i;
        float v  = vbase[c * Tv + t];
        float xa = (v * aw[c] + ab[c] - ma) * rsa * ag[c] + abeta[c];
        float xr = (v * rw[c] + rb[c] - mr) * rsr * rg[c] + rbeta[c];

        float m = xa;
        for (int off = 32; off; off >>= 1) m = fmaxf(m, __shfl_xor(m, off));
        float e = expf(xa - m);
        float sum = e;
        for (int off = 32; off; off >>= 1) sum += __shfl_xor(sum, off);

        const size_t idx = (size_t)b * VID_PER_B + (size_t)c * Tv + t;
        att_out[idx] = e / sum;
        vr_out[idx]  = xr;
    }
}

// ------------------------------------------------------------------
// Kernel 3: fused output. Each block covers 1024 contiguous float4 =
// exactly 1/8 of one (b,c) plane -> c is block-uniform (scalar coef
// loads). Nontemporal stores keep audio L3-resident.
// ------------------------------------------------------------------
__global__ __launch_bounds__(256) void k_fuse(
    const float* __restrict__ audio,
    const float* __restrict__ ws,
    float* __restrict__ out)
{
    const int blk = blockIdx.x;
    const int tid = threadIdx.x;
    const f32x4* a4 = reinterpret_cast<const f32x4*>(audio);
    f32x4*       o4 = reinterpret_cast<f32x4*>(out);

    const size_t bc = (size_t)(blk >> 3);       // b*Ca + c  (8 blocks per plane)
    const int    c  = (int)(bc & (size_t)(Ca - 1));
    const int    t_base = (blk & 7) * 32;       // plane-local t offset

    const float sv = ws[WS_COEF + c];
    const float bv = ws[WS_COEF + 512 + c];
    const float sg = ws[WS_COEF + 1024 + c];
    const float bg = ws[WS_COEF + 1536 + c];
    const float* att = ws + WS_ATT + bc * Tv;
    const float* vr  = ws + WS_VR  + bc * Tv;

    #pragma unroll
    for (int k = 0; k < 4; ++k) {
        const size_t i = (size_t)blk * 1024 + tid + (size_t)k * 256;
        const int    t = t_base + k * 8 + (tid >> 5);
        const float av = att[t >> 2];
        const float vv = vr[t >> 2];

        f32x4 a = a4[i];
        f32x4 r;
        r.x = av * (a.x * sv + bv) + fmaxf(a.x * sg + bg, 0.f) * vv;
        r.y = av * (a.y * sv + bv) + fmaxf(a.y * sg + bg, 0.f) * vv;
        r.z = av * (a.z * sv + bv) + fmaxf(a.z * sg + bg, 0.f) * vv;
        r.w = av * (a.w * sv + bv) + fmaxf(a.w * sg + bg, 0.f) * vv;
        __builtin_nontemporal_store(r, &o4[i]);
    }
}

// ------------------------------------------------------------------
extern "C" void kernel_launch(void* const* d_in, const int* in_sizes, int n_in,
                              void* d_out, int out_size, void* d_ws, size_t ws_size,
                              hipStream_t stream) {
    const float* audio   = (const float*)d_in[0];
    const float* video   = (const float*)d_in[1];
    const float* value_w = (const float*)d_in[2];
    const float* value_g = (const float*)d_in[3];
    const float* value_b = (const float*)d_in[4];
    const float* gate_w  = (const float*)d_in[5];
    const float* gate_g  = (const float*)d_in[6];
    const float* gate_b  = (const float*)d_in[7];
    const float* att_w   = (const float*)d_in[8];
    const float* att_b   = (const float*)d_in[9];
    const float* att_g   = (const float*)d_in[10];
    const float* att_be  = (const float*)d_in[11];
    const float* res_w   = (const float*)d_in[12];
    const float* res_b   = (const float*)d_in[13];
    const float* res_g   = (const float*)d_in[14];
    const float* res_be  = (const float*)d_in[15];

    float* ws = (float*)d_ws;

    k_stats<<<2048, 256, 0, stream>>>(audio, ws);
    k_video<<<B, 1024, 0, stream>>>(video,
                                    value_w, value_g, value_b,
                                    gate_w, gate_g, gate_b,
                                    att_w, att_b, att_g, att_be,
                                    res_w, res_b, res_g, res_be, ws);
    const int blocks = B * Ca * T * Fa / 4 / 1024;   // 8192
    k_fuse<<<blocks, 256, 0, stream>>>(audio, ws, (float*)d_out);
}